// Round 1
// baseline (157.928 us; speedup 1.0000x reference)
//
#include <hip/hip_runtime.h>

#define ALPHA 0.3f
#define NT    50
#define B_    16
#define S_    160
#define RR    40
#define NPAIR (B_ * S_ * S_)      // 409600
#define NSEG  (NT * NT)           // 2500
#define NREL  (NPAIR * RR)        // 16384000

__global__ void zero_tab(float* __restrict__ tab, int n) {
    int i = blockIdx.x * blockDim.x + threadIdx.x;
    if (i < n) tab[i] = 0.0f;
}

__device__ __forceinline__ int pair_key(const int* __restrict__ tags, int pair) {
    int b   = pair / (S_ * S_);
    int rem = pair % (S_ * S_);
    int p1  = rem / S_;
    int p2  = rem % S_;
    return tags[b * S_ + p1] * NT + tags[b * S_ + p2];
}

// one thread per a_arc element (= one pair)
__global__ void hist_arc(const float* __restrict__ a_arc,
                         const int* __restrict__ adds,
                         float* __restrict__ tab_arc) {
    int i = blockIdx.x * blockDim.x + threadIdx.x;
    if (i >= NPAIR) return;
    int key = pair_key(adds, i);
    atomicAdd(tab_arc + key, a_arc[i]);
}

// one thread per a_rel element, fully coalesced reads
__global__ void hist_rel(const float* __restrict__ a_rel,
                         const int* __restrict__ adds,
                         float* __restrict__ tab_rel) {
    int e = blockIdx.x * blockDim.x + threadIdx.x;
    if (e >= NREL) return;
    int pair = e / RR;
    int r    = e - pair * RR;
    int key  = pair_key(adds, pair);
    atomicAdd(tab_rel + key * RR + r, a_rel[e]);
}

__global__ void apply_arc(const float* __restrict__ s_arc,
                          const int* __restrict__ pos,
                          const float* __restrict__ tab_arc,
                          float* __restrict__ out) {
    int i = blockIdx.x * blockDim.x + threadIdx.x;
    if (i >= NPAIR) return;
    int key = pair_key(pos, i);
    out[i] = s_arc[i] + ALPHA * tab_arc[key];
}

// one thread per float4 of s_rel
__global__ void apply_rel(const float4* __restrict__ s_rel,
                          const int* __restrict__ pos,
                          const float4* __restrict__ tab_rel,
                          float4* __restrict__ out) {
    int t = blockIdx.x * blockDim.x + threadIdx.x;  // float4 index
    if (t >= NREL / 4) return;
    int pair = t / (RR / 4);          // /10
    int q    = t - pair * (RR / 4);
    int key  = pair_key(pos, pair);
    float4 sv = s_rel[t];
    float4 tv = tab_rel[key * (RR / 4) + q];
    float4 o;
    o.x = sv.x + ALPHA * tv.x;
    o.y = sv.y + ALPHA * tv.y;
    o.z = sv.z + ALPHA * tv.z;
    o.w = sv.w + ALPHA * tv.w;
    out[t] = o;
}

extern "C" void kernel_launch(void* const* d_in, const int* in_sizes, int n_in,
                              void* d_out, int out_size, void* d_ws, size_t ws_size,
                              hipStream_t stream) {
    const float* a_arc = (const float*)d_in[0];
    const float* a_rel = (const float*)d_in[1];
    const float* s_arc = (const float*)d_in[2];
    const float* s_rel = (const float*)d_in[3];
    const int*   adds  = (const int*)d_in[4];
    const int*   pos   = (const int*)d_in[5];
    // n_tags (d_in[6]) is fixed at 50 per the reference setup; hardcoded as NT.

    float* tab_arc = (float*)d_ws;            // [NSEG]
    float* tab_rel = tab_arc + NSEG;          // [NSEG * RR], 16B-aligned (NSEG*4 = 10000)

    float* out_arc = (float*)d_out;           // [NPAIR]
    float* out_rel = out_arc + NPAIR;         // [NREL], 16B-aligned

    const int BLK = 256;
    int n_tab = NSEG * (RR + 1);

    zero_tab<<<(n_tab + BLK - 1) / BLK, BLK, 0, stream>>>(tab_arc, n_tab);

    hist_arc<<<(NPAIR + BLK - 1) / BLK, BLK, 0, stream>>>(a_arc, adds, tab_arc);
    hist_rel<<<(NREL + BLK - 1) / BLK, BLK, 0, stream>>>(a_rel, adds, tab_rel);

    apply_arc<<<(NPAIR + BLK - 1) / BLK, BLK, 0, stream>>>(s_arc, pos, tab_arc, out_arc);
    apply_rel<<<(NREL / 4 + BLK - 1) / BLK, BLK, 0, stream>>>(
        (const float4*)s_rel, pos, (const float4*)tab_rel, (float4*)out_rel);
}

// Round 2
// 129.970 us; speedup vs baseline: 1.2151x; 1.2151x over previous
//
#include <hip/hip_runtime.h>

#define ALPHA 0.3f
#define NT    50
#define B_    16
#define S_    160
#define RR    40
#define NROW  (B_ * S_)           // 2560 rows (b,p1)
#define NPAIR (B_ * S_ * S_)      // 409600
#define NSEG  (NT * NT)           // 2500
#define NREL  (NPAIR * RR)        // 16384000
#define NCOL  (NT * RR + NT)      // 2050 compact columns per row (rel + arc)
#define CW    2052                // padded C row stride (floats)

// ---------------- utility ----------------
__global__ void zero_tab(float* __restrict__ tab, int n) {
    int i = blockIdx.x * blockDim.x + threadIdx.x;
    if (i < n) tab[i] = 0.0f;
}

// --------- build per-t1 row lists (counting sort, single block) ---------
__global__ void build_lists(const int* __restrict__ adds,
                            int* __restrict__ rowstart,   // [NT+1]
                            int* __restrict__ rowlist) {  // [NROW]
    __shared__ int cnt[NT];
    __shared__ int start[NT + 1];
    __shared__ int cur[NT];
    int tid = threadIdx.x;
    if (tid < NT) cnt[tid] = 0;
    __syncthreads();
    for (int i = tid; i < NROW; i += blockDim.x) atomicAdd(&cnt[adds[i]], 1);
    __syncthreads();
    if (tid == 0) {
        int s = 0;
        for (int t = 0; t < NT; t++) { start[t] = s; s += cnt[t]; }
        start[NT] = s;
    }
    __syncthreads();
    if (tid < NT) cur[tid] = start[tid];
    if (tid < NT + 1) rowstart[tid] = start[tid];
    __syncthreads();
    for (int i = tid; i < NROW; i += blockDim.x) {
        int slot = atomicAdd(&cur[adds[i]], 1);
        rowlist[slot] = i;
    }
}

// --------- stage 1: per-(b,p1)-row LDS-private histogram ---------
// MODE 0: write compact partial row to C (no global atomics)
// MODE 1: atomic-flush straight into tab_arc/tab_rel
template <int MODE>
__global__ __launch_bounds__(256) void stage1(const float* __restrict__ a_arc,
                                              const float4* __restrict__ a_rel4,
                                              const int* __restrict__ adds,
                                              float* __restrict__ C,
                                              float* __restrict__ tab_arc,
                                              float* __restrict__ tab_rel) {
    __shared__ float acc[NT * 41];   // [t2][r] rel in 0..39, arc in col 40
    __shared__ int   t2c[S_];
    int tid = threadIdx.x;
    int row = blockIdx.x;            // = b*S_ + p1
    int b   = row / S_;

    for (int i = tid; i < NT * 41; i += 256) acc[i] = 0.0f;
    if (tid < S_) t2c[tid] = adds[b * S_ + tid];
    __syncthreads();

    // arc: 160 scalars
    if (tid < S_) atomicAdd(&acc[t2c[tid] * 41 + 40], a_arc[row * S_ + tid]);

    // rel: 1600 float4 (r-dim stride 40 is 4-divisible -> all 4 share p2)
    const float4* arow = a_rel4 + row * (S_ * RR / 4);
    for (int e4 = tid; e4 < S_ * RR / 4; e4 += 256) {
        float4 v = arow[e4];
        int p2   = e4 / (RR / 4);            // e4/10
        int r    = (e4 - p2 * (RR / 4)) * 4; // 0,4,...,36
        float* dst = &acc[t2c[p2] * 41 + r];
        atomicAdd(dst + 0, v.x);
        atomicAdd(dst + 1, v.y);
        atomicAdd(dst + 2, v.z);
        atomicAdd(dst + 3, v.w);
    }
    __syncthreads();

    if (MODE == 0) {
        float* crow = C + row * CW;
        for (int c = tid; c < NCOL; c += 256) {
            int idx;
            if (c < NT * RR) { int t2 = c / RR; idx = t2 * 41 + (c - t2 * RR); }
            else             { idx = (c - NT * RR) * 41 + 40; }
            crow[c] = acc[idx];
        }
    } else {
        int t1 = t2c[row - b * S_];   // adds[b, p1]
        for (int c = tid; c < NCOL; c += 256) {
            if (c < NT * RR) {
                int t2 = c / RR;
                float v = acc[t2 * 41 + (c - t2 * RR)];
                atomicAdd(&tab_rel[t1 * (NT * RR) + c], v);
            } else {
                int t2 = c - NT * RR;
                atomicAdd(&tab_arc[t1 * NT + t2], acc[t2 * 41 + 40]);
            }
        }
    }
}

// --------- stage 2: reduce C rows grouped by t1 (no atomics) ---------
__global__ __launch_bounds__(128) void stage2(const float* __restrict__ C,
                                              const int* __restrict__ rowstart,
                                              const int* __restrict__ rowlist,
                                              float* __restrict__ tab_arc,
                                              float* __restrict__ tab_rel) {
    __shared__ int lrows[128];
    int t1 = blockIdx.y;
    int c  = blockIdx.x * 128 + threadIdx.x;
    int s0 = rowstart[t1], s1 = rowstart[t1 + 1];
    float acc = 0.0f;
    for (int base = s0; base < s1; base += 128) {
        int n = min(128, s1 - base);
        __syncthreads();
        if (threadIdx.x < n) lrows[threadIdx.x] = rowlist[base + threadIdx.x];
        __syncthreads();
        if (c < NCOL) {
            for (int j = 0; j < n; j++) acc += C[lrows[j] * CW + c];
        }
    }
    if (c >= NCOL) return;
    if (c < NT * RR) tab_rel[t1 * (NT * RR) + c] = acc;
    else             tab_arc[t1 * NT + (c - NT * RR)] = acc;
}

// --------- apply ---------
template <bool KEYS>
__global__ void apply_arc(const float* __restrict__ s_arc,
                          const int* __restrict__ pos,
                          const float* __restrict__ tab_arc,
                          float* __restrict__ out,
                          int* __restrict__ keys) {
    int i = blockIdx.x * blockDim.x + threadIdx.x;
    if (i >= NPAIR) return;
    int b   = i / (S_ * S_);
    int rem = i - b * (S_ * S_);
    int p1  = rem / S_;
    int p2  = rem - p1 * S_;
    int key = pos[b * S_ + p1] * NT + pos[b * S_ + p2];
    if (KEYS) keys[i] = key;
    out[i] = s_arc[i] + ALPHA * tab_arc[key];
}

template <bool KEYS>
__global__ void apply_rel(const float4* __restrict__ s_rel,
                          const int* __restrict__ pos,
                          const int* __restrict__ keys,
                          const float4* __restrict__ tab_rel4,
                          float4* __restrict__ out) {
    int t = blockIdx.x * blockDim.x + threadIdx.x;   // float4 index
    if (t >= NREL / 4) return;
    int pair = t / (RR / 4);
    int q    = t - pair * (RR / 4);
    int key;
    if (KEYS) {
        key = keys[pair];
    } else {
        int b   = pair / (S_ * S_);
        int rem = pair - b * (S_ * S_);
        int p1  = rem / S_;
        int p2  = rem - p1 * S_;
        key = pos[b * S_ + p1] * NT + pos[b * S_ + p2];
    }
    float4 sv = s_rel[t];
    float4 tv = tab_rel4[key * (RR / 4) + q];
    float4 o;
    o.x = sv.x + ALPHA * tv.x;
    o.y = sv.y + ALPHA * tv.y;
    o.z = sv.z + ALPHA * tv.z;
    o.w = sv.w + ALPHA * tv.w;
    out[t] = o;
}

extern "C" void kernel_launch(void* const* d_in, const int* in_sizes, int n_in,
                              void* d_out, int out_size, void* d_ws, size_t ws_size,
                              hipStream_t stream) {
    const float*  a_arc = (const float*)d_in[0];
    const float4* a_rel = (const float4*)d_in[1];
    const float*  s_arc = (const float*)d_in[2];
    const float4* s_rel = (const float4*)d_in[3];
    const int*    adds  = (const int*)d_in[4];
    const int*    pos   = (const int*)d_in[5];

    // workspace layout
    float* tab_arc  = (float*)d_ws;                       // NSEG
    float* tab_rel  = tab_arc + NSEG;                     // NSEG*RR
    int*   keys     = (int*)(tab_rel + NSEG * RR);        // NPAIR
    int*   rowstart = keys + NPAIR;                       // NT+1 (padded 64)
    int*   rowlist  = rowstart + 64;                      // NROW
    float* C        = (float*)(rowlist + NROW);           // NROW*CW

    size_t need_low  = (size_t)(NSEG * (RR + 1)) * 4;
    size_t need_mid  = need_low + (size_t)NPAIR * 4;
    size_t need_full = need_mid + (size_t)(64 + NROW) * 4 + (size_t)NROW * CW * 4;

    float* out_arc = (float*)d_out;            // NPAIR
    float4* out_rel = (float4*)(out_arc + NPAIR); // NREL/4

    const int BLK = 256;

    if (ws_size >= need_full) {
        // fully deterministic two-stage path, zero global atomics
        build_lists<<<1, 256, 0, stream>>>(adds, rowstart, rowlist);
        stage1<0><<<NROW, 256, 0, stream>>>(a_arc, a_rel, adds, C, tab_arc, tab_rel);
        dim3 g2((NCOL + 127) / 128, NT);
        stage2<<<g2, 128, 0, stream>>>(C, rowstart, rowlist, tab_arc, tab_rel);
        apply_arc<true><<<(NPAIR + BLK - 1) / BLK, BLK, 0, stream>>>(
            s_arc, pos, tab_arc, out_arc, keys);
        apply_rel<true><<<(NREL / 4 + BLK - 1) / BLK, BLK, 0, stream>>>(
            s_rel, pos, keys, (const float4*)tab_rel, out_rel);
    } else if (ws_size >= need_mid) {
        int n_tab = NSEG * (RR + 1);
        zero_tab<<<(n_tab + BLK - 1) / BLK, BLK, 0, stream>>>(tab_arc, n_tab);
        stage1<1><<<NROW, 256, 0, stream>>>(a_arc, a_rel, adds, nullptr, tab_arc, tab_rel);
        apply_arc<true><<<(NPAIR + BLK - 1) / BLK, BLK, 0, stream>>>(
            s_arc, pos, tab_arc, out_arc, keys);
        apply_rel<true><<<(NREL / 4 + BLK - 1) / BLK, BLK, 0, stream>>>(
            s_rel, pos, keys, (const float4*)tab_rel, out_rel);
    } else {
        int n_tab = NSEG * (RR + 1);
        zero_tab<<<(n_tab + BLK - 1) / BLK, BLK, 0, stream>>>(tab_arc, n_tab);
        stage1<1><<<NROW, 256, 0, stream>>>(a_arc, a_rel, adds, nullptr, tab_arc, tab_rel);
        apply_arc<false><<<(NPAIR + BLK - 1) / BLK, BLK, 0, stream>>>(
            s_arc, pos, tab_arc, out_arc, nullptr);
        apply_rel<false><<<(NREL / 4 + BLK - 1) / BLK, BLK, 0, stream>>>(
            s_rel, pos, nullptr, (const float4*)tab_rel, out_rel);
    }
}

// Round 3
// 83.116 us; speedup vs baseline: 1.9001x; 1.5637x over previous
//
#include <hip/hip_runtime.h>

#define ALPHA 0.3f
#define NT    50
#define B_    16
#define S_    160
#define RR    40
#define NROW  (B_ * S_)           // 2560
#define NPAIR (B_ * S_ * S_)      // 409600
#define NSEG  (NT * NT)           // 2500
#define NREL  (NPAIR * RR)        // 16384000
#define NCOL  (NT * RR + NT)      // 2050 compact cols per row (rel + arc)
#define CW    2052                // padded C row stride (floats); 8208B, 16B-aligned

__global__ void zero_tab(float* __restrict__ tab, int n) {
    int i = blockIdx.x * blockDim.x + threadIdx.x;
    if (i < n) tab[i] = 0.0f;
}

// ---- per-batch column lists: deterministic counting sort of adds[b][:]----
__global__ void build_lists(const int* __restrict__ adds,
                            int* __restrict__ colstart,   // [B_][64]
                            int* __restrict__ collist) {  // [B_][S_]
    __shared__ int tags[S_];
    __shared__ int cnt[NT];
    __shared__ int start[NT + 1];
    int b   = blockIdx.x;
    int tid = threadIdx.x;
    if (tid < S_) tags[tid] = adds[b * S_ + tid];
    __syncthreads();
    if (tid < NT) {
        int c = 0;
        for (int i = 0; i < S_; i++) c += (tags[i] == tid);
        cnt[tid] = c;
    }
    __syncthreads();
    if (tid == 0) {
        int s = 0;
        for (int t = 0; t < NT; t++) { start[t] = s; s += cnt[t]; }
        start[NT] = s;
    }
    __syncthreads();
    if (tid <= NT) colstart[b * 64 + tid] = start[tid];
    if (tid < NT) {
        int slot = start[tid];
        for (int i = 0; i < S_; i++)
            if (tags[i] == tid) collist[b * S_ + slot++] = i;
    }
}

// ---- stage 1: per-row gather-reduce, register accumulation, NO atomics ----
// TO_C=1: write compact partial row to C.  TO_C=0: atomic-flush to tab (fallback).
template <int TO_C>
__global__ __launch_bounds__(256) void stage1(const float* __restrict__ a_arc,
                                              const float4* __restrict__ a_rel4,
                                              const int* __restrict__ adds,
                                              const int* __restrict__ colstart,
                                              const int* __restrict__ collist,
                                              float* __restrict__ C,
                                              float* __restrict__ tab_arc,
                                              float* __restrict__ tab_rel) {
    __shared__ int s_start[NT + 1];
    __shared__ int s_list[S_];
    int row = blockIdx.x;            // b*S_ + p1
    int b   = row / S_;
    int tid = threadIdx.x;
    if (tid <= NT) s_start[tid] = colstart[b * 64 + tid];
    if (tid < S_)  s_list[tid]  = collist[b * S_ + tid];
    __syncthreads();

    const float4* arow  = a_rel4 + (size_t)row * (S_ * RR / 4);
    const float*  aarow = a_arc + row * S_;
    int t1 = TO_C ? 0 : adds[row];

    // rel: 500 float4 cells (t2, r-quad)
    for (int cell = tid; cell < NT * (RR / 4); cell += 256) {
        int t2 = cell / (RR / 4);
        int q  = cell - t2 * (RR / 4);
        float4 acc = make_float4(0.f, 0.f, 0.f, 0.f);
        int e1 = s_start[t2 + 1];
        for (int e = s_start[t2]; e < e1; ++e) {
            float4 v = arow[s_list[e] * (RR / 4) + q];
            acc.x += v.x; acc.y += v.y; acc.z += v.z; acc.w += v.w;
        }
        if (TO_C) {
            ((float4*)(C + (size_t)row * CW))[cell] = acc;
        } else {
            float* dst = tab_rel + (size_t)t1 * (NT * RR) + cell * 4;
            atomicAdd(dst + 0, acc.x); atomicAdd(dst + 1, acc.y);
            atomicAdd(dst + 2, acc.z); atomicAdd(dst + 3, acc.w);
        }
    }
    // arc: 50 cells
    if (tid < NT) {
        float acc = 0.f;
        int e1 = s_start[tid + 1];
        for (int e = s_start[tid]; e < e1; ++e) acc += aarow[s_list[e]];
        if (TO_C) C[(size_t)row * CW + NT * RR + tid] = acc;
        else      atomicAdd(tab_arc + t1 * NT + tid, acc);
    }
}

// ---- stage 2: reduce C rows grouped by t1 via per-batch lists, NO atomics ----
__global__ __launch_bounds__(256) void stage2(const float* __restrict__ C,
                                              const int* __restrict__ adds,
                                              const int* __restrict__ colstart,
                                              const int* __restrict__ collist,
                                              float* __restrict__ tab_arc,
                                              float* __restrict__ tab_rel) {
    int t1 = blockIdx.y;
    int c  = blockIdx.x * 256 + threadIdx.x;
    if (c >= NCOL) return;
    float acc = 0.f;
    for (int b = 0; b < B_; b++) {
        int s0 = colstart[b * 64 + t1], s1 = colstart[b * 64 + t1 + 1];
        for (int j = s0; j < s1; j++) {
            int row = b * S_ + collist[b * S_ + j];
            acc += C[(size_t)row * CW + c];
        }
    }
    if (c < NT * RR) tab_rel[t1 * (NT * RR) + c] = acc;
    else             tab_arc[t1 * NT + (c - NT * RR)] = acc;
}

// ---- apply ----
template <bool KEYS>
__global__ void apply_arc(const float* __restrict__ s_arc,
                          const int* __restrict__ pos,
                          const float* __restrict__ tab_arc,
                          float* __restrict__ out,
                          int* __restrict__ keys) {
    int i = blockIdx.x * blockDim.x + threadIdx.x;
    if (i >= NPAIR) return;
    int b   = i / (S_ * S_);
    int rem = i - b * (S_ * S_);
    int p1  = rem / S_;
    int p2  = rem - p1 * S_;
    int key = pos[b * S_ + p1] * NT + pos[b * S_ + p2];
    if (KEYS) keys[i] = key;
    out[i] = s_arc[i] + ALPHA * tab_arc[key];
}

template <bool KEYS>
__global__ void apply_rel(const float4* __restrict__ s_rel,
                          const int* __restrict__ pos,
                          const int* __restrict__ keys,
                          const float4* __restrict__ tab_rel4,
                          float4* __restrict__ out) {
    int t = blockIdx.x * blockDim.x + threadIdx.x;   // float4 index
    if (t >= NREL / 4) return;
    int pair = t / (RR / 4);
    int q    = t - pair * (RR / 4);
    int key;
    if (KEYS) {
        key = keys[pair];
    } else {
        int b   = pair / (S_ * S_);
        int rem = pair - b * (S_ * S_);
        int p1  = rem / S_;
        int p2  = rem - p1 * S_;
        key = pos[b * S_ + p1] * NT + pos[b * S_ + p2];
    }
    float4 sv = s_rel[t];
    float4 tv = tab_rel4[key * (RR / 4) + q];
    float4 o;
    o.x = sv.x + ALPHA * tv.x;
    o.y = sv.y + ALPHA * tv.y;
    o.z = sv.z + ALPHA * tv.z;
    o.w = sv.w + ALPHA * tv.w;
    out[t] = o;
}

extern "C" void kernel_launch(void* const* d_in, const int* in_sizes, int n_in,
                              void* d_out, int out_size, void* d_ws, size_t ws_size,
                              hipStream_t stream) {
    const float*  a_arc = (const float*)d_in[0];
    const float4* a_rel = (const float4*)d_in[1];
    const float*  s_arc = (const float*)d_in[2];
    const float4* s_rel = (const float4*)d_in[3];
    const int*    adds  = (const int*)d_in[4];
    const int*    pos   = (const int*)d_in[5];

    // workspace layout
    float* tab_arc  = (float*)d_ws;                       // NSEG
    float* tab_rel  = tab_arc + NSEG;                     // NSEG*RR
    int*   keys     = (int*)(tab_rel + NSEG * RR);        // NPAIR
    int*   colstart = keys + NPAIR;                       // B_*64
    int*   collist  = colstart + B_ * 64;                 // B_*S_
    float* C        = (float*)(collist + B_ * S_);        // NROW*CW
    // align C to 16B
    C = (float*)(((uintptr_t)C + 15) & ~(uintptr_t)15);

    size_t need_lists = (size_t)(NSEG * (RR + 1)) * 4 + (size_t)NPAIR * 4
                      + (size_t)(B_ * 64 + B_ * S_) * 4 + 16;
    size_t need_full  = need_lists + (size_t)NROW * CW * 4;

    float*  out_arc = (float*)d_out;                 // NPAIR
    float4* out_rel = (float4*)(out_arc + NPAIR);    // NREL/4

    const int BLK = 256;

    build_lists<<<B_, 192, 0, stream>>>(adds, colstart, collist);

    if (ws_size >= need_full) {
        // deterministic two-stage path, zero atomics anywhere
        stage1<1><<<NROW, 256, 0, stream>>>(a_arc, a_rel, adds, colstart, collist,
                                            C, nullptr, nullptr);
        dim3 g2((NCOL + 255) / 256, NT);
        stage2<<<g2, 256, 0, stream>>>(C, adds, colstart, collist, tab_arc, tab_rel);
    } else {
        int n_tab = NSEG * (RR + 1);
        zero_tab<<<(n_tab + BLK - 1) / BLK, BLK, 0, stream>>>(tab_arc, n_tab);
        stage1<0><<<NROW, 256, 0, stream>>>(a_arc, a_rel, adds, colstart, collist,
                                            nullptr, tab_arc, tab_rel);
    }

    bool have_keys = ws_size >= need_lists;
    if (have_keys) {
        apply_arc<true><<<(NPAIR + BLK - 1) / BLK, BLK, 0, stream>>>(
            s_arc, pos, tab_arc, out_arc, keys);
        apply_rel<true><<<(NREL / 4 + BLK - 1) / BLK, BLK, 0, stream>>>(
            s_rel, pos, keys, (const float4*)tab_rel, out_rel);
    } else {
        apply_arc<false><<<(NPAIR + BLK - 1) / BLK, BLK, 0, stream>>>(
            s_arc, pos, tab_arc, out_arc, nullptr);
        apply_rel<false><<<(NREL / 4 + BLK - 1) / BLK, BLK, 0, stream>>>(
            s_rel, pos, nullptr, (const float4*)tab_rel, out_rel);
    }
}